// Round 2
// baseline (248.825 us; speedup 1.0000x reference)
//
#include <hip/hip_runtime.h>
#include <math.h>

#define PI_D 3.14159265358979323846
#define PI_F 3.14159265358979323846f

typedef _Float16 half8 __attribute__((ext_vector_type(8)));
typedef _Float16 half4v __attribute__((ext_vector_type(4)));
typedef float floatx4 __attribute__((ext_vector_type(4)));
#define MFMA16(a,b,c) __builtin_amdgcn_mfma_f32_16x16x32_f16(a,b,c,0,0,0)

// order-preserving float<->uint encoding for atomicMax on floats
__device__ __forceinline__ unsigned fenc(float f) {
  unsigned u = __float_as_uint(f);
  return (u & 0x80000000u) ? ~u : (u | 0x80000000u);
}
__device__ __forceinline__ float fdec(unsigned e) {
  return (e & 0x80000000u) ? __uint_as_float(e & 0x7FFFFFFFu)
                           : __uint_as_float(~e);
}

// ---------------- scatter + small prep (wq block0; sgs/WS/uftg/cnt zero block1) ----------------
__global__ void k_scatter(const float* __restrict__ inp,
                          const float* __restrict__ p_scale,
                          const float* __restrict__ p_sigma,
                          const float* __restrict__ p_A,
                          const float* __restrict__ p_ic,
                          const float* __restrict__ Wg,
                          float* __restrict__ ft, float* __restrict__ wq,
                          float* __restrict__ sgs, float* __restrict__ WS,
                          unsigned* __restrict__ uftg, unsigned* __restrict__ cnt) {
  int blk = blockIdx.x, t = threadIdx.x;
  if (blk == 0) {
    // quadrature weights, fp64 kept for bit-identical wq, k-sum spread
    // over 8 lanes per j (2 serial sins/lane instead of 17).
    double jj = 2.0*(double)(t >> 3) + 1.0;
    int kk = t & 7;
    double s = 0.0;
#pragma unroll
    for (int u = 0; u < 2; ++u) {
      double k2 = (double)(2*(kk + 8*u) + 1);
      s += sin(jj * k2 * (PI_D/64.0)) / k2;
    }
    s += __shfl_xor(s, 1, 64);
    s += __shfl_xor(s, 2, 64);
    s += __shfl_xor(s, 4, 64);
    if (kk == 0) wq[t >> 3] = (float)((2.0/16.0) * sin(PI_D * jj / 64.0) * s);
  } else if (blk == 1) {
    if (t == 0) *cnt = 0u;
    if (t < 64) {                                  // sgs[c] = sum_g Wg[c,g]
      float s = 0.f;
      for (int g = 0; g < 32; ++g) s += Wg[t*32 + g];
      sgs[t] = s;
    } else if (t < 192) {                          // zero WS (512 floats, float4)
      ((float4*)WS)[t - 64] = make_float4(0.f, 0.f, 0.f, 0.f);
    } else {                                       // zero uftg (256 uints, uint4)
      uint4 z; z.x = z.y = z.z = z.w = 0u;
      ((uint4*)uftg)[t - 192] = z;
    }
  }
  int i = blk * 256 + t;                           // 0 .. 262143
  float scale = p_scale[0];
  float sigma = p_sigma[0];
  float A     = p_A[0];
  float icomp = p_ic[0];
  int b = i >> 15;
  float x = inp[i*3+0];
  float y = inp[i*3+1];
  float z = inp[i*3+2];
  float r = sqrtf(x*x + y*y + z*z);
  r = fmaxf(r, 0.1f);
  float ctv = fminf(fmaxf(z / r, -1.0f), 1.0f);
  float theta = acosf(ctv);
  float phi = atan2f(y, x) + PI_F;
  float ct = theta * (32.0f / PI_F);
  float cp = phi * (32.0f / (2.0f * PI_F));
  float cr = r / scale * 8.0f;
  int it = (int)floorf(ct); it = min(max(it, 0), 31);
  int ip = (int)floorf(cp); ip = min(max(ip, 0), 31);
  int ir = (int)floorf(cr); ir = min(max(ir, 0), 7);
  float dt = ct - ((float)it + icomp);
  float dp = cp - ((float)ip + icomp);
  float dr = cr - ((float)ir + icomp);
  float d2 = dt*dt + dp*dp + dr*dr;
  float w = A * expf(-d2 / (2.0f * sigma * sigma));
  atomicAdd(&ft[((b*8 + ir)*32 + it)*32 + ip], w);
}

// ---------------- fused conv1+conv2+reduce + V/W2 fragment prep ----------------
__global__ __launch_bounds__(512) void k_conv12(
    const float* __restrict__ ft, const float* __restrict__ W1,
    const float* __restrict__ b1, const float* __restrict__ W2,
    const float* __restrict__ b2, const float* __restrict__ wq,
    const float* __restrict__ Wg, const float* __restrict__ Wc31,
    const float* __restrict__ Wc32,
    _Float16* __restrict__ VswH, _Float16* __restrict__ VswL,
    _Float16* __restrict__ W2swH, _Float16* __restrict__ W2swL,
    _Float16* __restrict__ h2H, _Float16* __restrict__ h2L,
    float* __restrict__ WS) {
  __shared__ __align__(16) float ftt[8][5][32];    // [ic][xx][y]
  __shared__ __align__(16) float h1t[32][3][32];   // [ic2][xr][y]
  __shared__ __align__(16) float W1s[72*34];       // [rest][oc2], pad 34 (b64 reads)
  __shared__ __align__(16) float W2s[288*68];      // [rest][oc], pad 68 (b128 reads)
  int blk = blockIdx.x;
  int b = blk >> 5, xt = blk & 31;
  int t = threadIdx.x;                             // 512

  // ---- fragment prep (for k_head), disjoint chunks ----
  {
    int flat = blk * 512 + t;                      // 0 .. 131071
    int jj = flat & 7;
    int l  = (flat >> 3) & 63;
    int rest = flat >> 9;                          // mt*2 + ks
    int ks = rest & 1, mt = rest >> 1;
    int c = ks*32 + (l >> 4)*8 + jj;
    int m = mt*16 + (l & 15);                      // m = g*64 + d
    int g = m >> 6, d = m & 63;
    float val = Wg[c*32 + g] * Wc31[d*128 + c];
    _Float16 hi = (_Float16)val;
    VswH[flat] = hi;
    VswL[flat] = (_Float16)(val - (float)hi);
    if (flat < 2048) {                             // W2 A-frags (M-side = e)
      int ks2 = rest & 1, mt2 = rest >> 1;
      int e = mt2*16 + (l & 15);
      int dd = ks2*32 + (l >> 4)*8 + jj;
      float v2 = Wc32[e*64 + dd];
      _Float16 h2i = (_Float16)v2;
      W2swH[flat] = h2i;
      W2swL[flat] = (_Float16)(v2 - (float)h2i);
    }
  }

  // ---- coalesced weight staging w/ padded transpose ----
  for (int idx = t; idx < 2304; idx += 512) {      // W1: read flat (coalesced)
    int oc2 = idx / 72, rest = idx % 72;
    W1s[rest*34 + oc2] = W1[idx];
  }
  for (int idx = t; idx < 4608; idx += 512) {      // W2: float4 coalesced
    float4 v4 = ((const float4*)W2)[idx];
    int base = idx * 4;
    int oc = base / 288, r0 = base % 288;
    W2s[(r0+0)*68 + oc] = v4.x;
    W2s[(r0+1)*68 + oc] = v4.y;
    W2s[(r0+2)*68 + oc] = v4.z;
    W2s[(r0+3)*68 + oc] = v4.w;
  }
  for (int idx = t; idx < 1280; idx += 512) {
    int y = idx & 31, xx = (idx >> 5) % 5, ic = idx / 160;
    int xg = xt + xx - 2;
    ftt[ic][xx][y] = ((unsigned)xg < 32u) ? ft[b*8192 + ic*1024 + xg*32 + y] : 0.f;
  }
  __syncthreads();

  // ---- conv1: thread owns oc2 = grp*2+{0,1}, xr = 0..2, one y ----
  {
    int y = t & 31, grp = t >> 5;
    float acc[2][3];
    float bb0 = b1[grp*2+0], bb1 = b1[grp*2+1];
#pragma unroll
    for (int xr = 0; xr < 3; ++xr) { acc[0][xr] = bb0; acc[1][xr] = bb1; }
    for (int ic = 0; ic < 8; ++ic) {
      float v[5][3];
#pragma unroll
      for (int dyi = 0; dyi < 3; ++dyi) {
        int yy = y + dyi - 1;
        bool ok = ((unsigned)yy < 32u);
        int yc = min(max(yy, 0), 31);
#pragma unroll
        for (int xx = 0; xx < 5; ++xx) {
          float tv = ftt[ic][xx][yc];
          v[xx][dyi] = ok ? tv : 0.f;
        }
      }
#pragma unroll
      for (int k = 0; k < 9; ++k) {
        float2 w01 = *(const float2*)&W1s[(ic*9 + k)*34 + grp*2];
        int dx = k / 3, dy = k % 3;
#pragma unroll
        for (int xr = 0; xr < 3; ++xr) {
          float vv = v[xr + dx][dy];
          acc[0][xr] = fmaf(vv, w01.x, acc[0][xr]);
          acc[1][xr] = fmaf(vv, w01.y, acc[1][xr]);
        }
      }
    }
#pragma unroll
    for (int xr = 0; xr < 3; ++xr) {
      int xg = xt + xr - 1;
      bool ok = ((unsigned)xg < 32u);
      h1t[grp*2+0][xr][y] = ok ? fmaxf(acc[0][xr], 0.f) : 0.f;
      h1t[grp*2+1][xr][y] = ok ? fmaxf(acc[1][xr], 0.f) : 0.f;
    }
  }
  __syncthreads();

  // ---- conv2 + f16-split store + reduce: thread owns oc = og*4..+3, one y ----
  {
    int y = t & 31, og = t >> 5, oc0 = og*4;
    float a0 = b2[oc0+0], a1 = b2[oc0+1], a2 = b2[oc0+2], a3 = b2[oc0+3];
    for (int ic2 = 0; ic2 < 32; ++ic2) {
      float v[3][3];
#pragma unroll
      for (int dyi = 0; dyi < 3; ++dyi) {
        int yy = y + dyi - 1;
        bool ok = ((unsigned)yy < 32u);
        int yc = min(max(yy, 0), 31);
#pragma unroll
        for (int xxi = 0; xxi < 3; ++xxi) {
          float tv = h1t[ic2][xxi][yc];
          v[xxi][dyi] = ok ? tv : 0.f;
        }
      }
#pragma unroll
      for (int k = 0; k < 9; ++k) {
        float4 wv = *(const float4*)&W2s[(ic2*9 + k)*68 + oc0];
        float vv = v[k/3][k%3];
        a0 = fmaf(vv, wv.x, a0);
        a1 = fmaf(vv, wv.y, a1);
        a2 = fmaf(vv, wv.z, a2);
        a3 = fmaf(vv, wv.w, a3);
      }
    }
    float r0 = fmaxf(a0, 0.f), r1 = fmaxf(a1, 0.f);
    float r2 = fmaxf(a2, 0.f), r3 = fmaxf(a3, 0.f);
    // store h2 pre-split to f16 hi/lo in k_head B-fragment layout:
    // frag idx = (((b*32+x)*2 + ks)*4 + quad)*32 + col, elem j; c = ks*32+quad*8+j
    int ks = og >> 3, quad = (og >> 1) & 3, jb = (og & 1) * 4;
    int fidx = (((b*32 + xt)*2 + ks)*4 + quad)*32 + y;
    half4v hv, lv;
    hv[0] = (_Float16)r0; lv[0] = (_Float16)(r0 - (float)hv[0]);
    hv[1] = (_Float16)r1; lv[1] = (_Float16)(r1 - (float)hv[1]);
    hv[2] = (_Float16)r2; lv[2] = (_Float16)(r2 - (float)hv[2]);
    hv[3] = (_Float16)r3; lv[3] = (_Float16)(r3 - (float)hv[3]);
    *(half4v*)&h2H[(size_t)fidx*8 + jb] = hv;
    *(half4v*)&h2L[(size_t)fidx*8 + jb] = lv;
    float wqv = wq[y];
    float s0 = r0*wqv, s1 = r1*wqv, s2 = r2*wqv, s3 = r3*wqv;
#pragma unroll
    for (int m = 1; m < 32; m <<= 1) {
      s0 += __shfl_xor(s0, m, 64);
      s1 += __shfl_xor(s1, m, 64);
      s2 += __shfl_xor(s2, m, 64);
      s3 += __shfl_xor(s3, m, 64);
    }
    if ((t & 31) == 0) {
      atomicAdd(&WS[b*64 + oc0+0], s0);
      atomicAdd(&WS[b*64 + oc0+1], s1);
      atomicAdd(&WS[b*64 + oc0+2], s2);
      atomicAdd(&WS[b*64 + oc0+3], s3);
    }
  }
}

// ---------------- head (MFMA): grid 512 = b(8)*x(32)*h(2), h = g-half ----
// final ftg max folded in via flip-encoded atomicMax + last-block convert
__global__ __launch_bounds__(512, 4) void k_head(
    const _Float16* __restrict__ h2H, const _Float16* __restrict__ h2L,
    const float* __restrict__ WS, const float* __restrict__ sgs,
    const float* __restrict__ Wc31, const float* __restrict__ bc31,
    const float* __restrict__ bc32,
    const half8* __restrict__ VswH, const half8* __restrict__ VswL,
    const half8* __restrict__ W2swH, const half8* __restrict__ W2swL,
    float* __restrict__ out, unsigned* __restrict__ uftg,
    unsigned* __restrict__ cnt, float* __restrict__ ftg) {
  __shared__ __align__(16) _Float16 h3H[512*72];   // [rowc=y*16+gl][d sw], 72 KiB
  __shared__ float Ks[64];
  __shared__ float vbuf2[128];
  __shared__ int sdone;
  int blk = blockIdx.x;            // 512
  int b = blk >> 6, x = (blk >> 1) & 31, h = blk & 1;
  int t = threadIdx.x;             // 512 = 8 waves
  int lane = t & 63, w = t >> 6;
  int n16 = lane & 15, quad = lane >> 4;

  // Ks[d] = bc31[d] + sum_c Wc31[d,64+c]*sgs[c]*WS[b,c], 4 lanes per d
  if (t < 256) {
    int d = t >> 2, q = t & 3;
    const float* wr  = Wc31 + d*128 + 64 + q*16;
    const float* sg  = sgs + q*16;
    const float* wsb = WS + b*64 + q*16;
    float acc = 0.f;
#pragma unroll
    for (int c = 0; c < 16; ++c)
      acc = fmaf(wr[c], sg[c]*wsb[c], acc);
    acc += __shfl_xor(acc, 1, 64);
    acc += __shfl_xor(acc, 2, 64);
    if (q == 0) Ks[d] = acc + bc31[d];
  }

  // GEMM1 B-frags: direct coalesced half8 loads (pre-split by k_conv12)
  half8 bh00, bh01, bh10, bh11, bl00, bl01, bl10, bl11;
  {
    const half8* H8 = (const half8*)h2H;
    const half8* L8 = (const half8*)h2L;
    int fo = ((b*32 + x)*8 + quad)*32;       // ks=0 base; ks=1 at +128
    bh00 = H8[fo + n16];        bh10 = H8[fo + 16 + n16];
    bl00 = L8[fo + n16];        bl10 = L8[fo + 16 + n16];
    bh01 = H8[fo + 128 + n16];  bh11 = H8[fo + 128 + 16 + n16];
    bl01 = L8[fo + 128 + n16];  bl11 = L8[fo + 128 + 16 + n16];
  }
  int mt2 = w & 1;
  half8 a2h0 = W2swH[(mt2*2 + 0)*64 + lane];
  half8 a2h1 = W2swH[(mt2*2 + 1)*64 + lane];
  half8 a2l0 = W2swL[(mt2*2 + 0)*64 + lane];
  half8 a2l1 = W2swL[(mt2*2 + 1)*64 + lane];
  float bias_e[4];
#pragma unroll
  for (int r = 0; r < 4; ++r) bias_e[r] = bc32[mt2*16 + quad*4 + r];
  __syncthreads();                 // Ks ready

  // ---- phase A: GEMM1, wave owns mt = h*64 + w*8 + i ----
  for (int i = 0; i < 8; ++i) {
    int mt = h*64 + w*8 + i;
    half8 ah0 = VswH[(mt*2 + 0)*64 + lane];
    half8 ah1 = VswH[(mt*2 + 1)*64 + lane];
    half8 al0 = VswL[(mt*2 + 0)*64 + lane];
    half8 al1 = VswL[(mt*2 + 1)*64 + lane];
    floatx4 acc0 = {0.f, 0.f, 0.f, 0.f};
    floatx4 acc1 = {0.f, 0.f, 0.f, 0.f};
    acc0 = MFMA16(ah0, bh00, acc0);  acc1 = MFMA16(ah0, bh10, acc1);
    acc0 = MFMA16(ah0, bl00, acc0);  acc1 = MFMA16(ah0, bl10, acc1);
    acc0 = MFMA16(al0, bh00, acc0);  acc1 = MFMA16(al0, bh10, acc1);
    acc0 = MFMA16(ah1, bh01, acc0);  acc1 = MFMA16(ah1, bh11, acc1);
    acc0 = MFMA16(ah1, bl01, acc0);  acc1 = MFMA16(ah1, bl11, acc1);
    acc0 = MFMA16(al1, bh01, acc0);  acc1 = MFMA16(al1, bh11, acc1);
    int g = mt >> 2, gl = g & 15;
    int dbase = (mt & 3)*16 + quad*4;
    float4 kv = *(const float4*)&Ks[dbase];
#pragma unroll
    for (int nt = 0; nt < 2; ++nt) {
      floatx4 a = nt ? acc1 : acc0;
      int y = nt*16 + n16;
      int rowc = y*16 + gl;
      int dsw = (dbase + y*8) & 63;
      half4v hv;
      hv[0] = (_Float16)fmaxf(a[0] + kv.x, 0.f);
      hv[1] = (_Float16)fmaxf(a[1] + kv.y, 0.f);
      hv[2] = (_Float16)fmaxf(a[2] + kv.z, 0.f);
      hv[3] = (_Float16)fmaxf(a[3] + kv.w, 0.f);
      *(half4v*)&h3H[rowc*72 + dsw] = hv;
    }
  }
  __syncthreads();
  // ---- phase B: GEMM2, wave owns nt2 = (w>>1)*8 + i (= y), e-tile mt2 ----
  float vmax[4] = {-3.4e38f, -3.4e38f, -3.4e38f, -3.4e38f};
  for (int i = 0; i < 8; ++i) {
    int nt2 = (w >> 1)*8 + i;
    int rowc = nt2*16 + n16;       // gl = n16
    int dsw0 = (quad*8 + nt2*8) & 63;
    int dsw1 = (32 + quad*8 + nt2*8) & 63;
    half8 b2h0 = *(const half8*)&h3H[rowc*72 + dsw0];
    half8 b2h1 = *(const half8*)&h3H[rowc*72 + dsw1];
    floatx4 acc = {0.f, 0.f, 0.f, 0.f};
    acc = MFMA16(a2h0, b2h0, acc);
    acc = MFMA16(a2l0, b2h0, acc);
    acc = MFMA16(a2h1, b2h1, acc);
    acc = MFMA16(a2l1, b2h1, acc);
    int y = nt2, g = h*16 + n16;
    size_t base = (((size_t)(b*32 + mt2*16 + quad*4))*1024 + (size_t)(x*32 + y))*32 + g;
#pragma unroll
    for (int r = 0; r < 4; ++r) {
      float v = acc[r] + bias_e[r];
      out[base + (size_t)r*32768] = v;
      vmax[r] = fmaxf(vmax[r], v);
    }
  }
  // block max over e
#pragma unroll
  for (int m = 1; m < 16; m <<= 1) {
#pragma unroll
    for (int r = 0; r < 4; ++r)
      vmax[r] = fmaxf(vmax[r], __shfl_xor(vmax[r], m, 64));
  }
  if (n16 == 0) {
#pragma unroll
    for (int r = 0; r < 4; ++r) vbuf2[w*16 + quad*4 + r] = vmax[r];
  }
  __syncthreads();
  if (t < 32) {
    int e = t, m2 = e >> 4, el = e & 15;
    float mm = fmaxf(fmaxf(vbuf2[(m2+0)*16 + el], vbuf2[(m2+2)*16 + el]),
                     fmaxf(vbuf2[(m2+4)*16 + el], vbuf2[(m2+6)*16 + el]));
    atomicMax(&uftg[b*32 + e], fenc(mm));
  }
  // last finishing block converts uftg -> ftg
  __syncthreads();
  __threadfence();
  if (t == 0) sdone = (atomicAdd(cnt, 1u) == 511u) ? 1 : 0;
  __syncthreads();
  if (sdone && t < 256) {
    unsigned ev = atomicAdd(&uftg[t], 0u);   // coherent RMW read
    ftg[t] = fdec(ev);
  }
}

extern "C" void kernel_launch(void* const* d_in, const int* in_sizes, int n_in,
                              void* d_out, int out_size, void* d_ws, size_t ws_size,
                              hipStream_t stream) {
  const float* inputs = (const float*)d_in[0];
  const float* scale  = (const float*)d_in[1];
  const float* sigma  = (const float*)d_in[2];
  const float* A      = (const float*)d_in[3];
  const float* icmp   = (const float*)d_in[4];
  // d_in[5]=res_pt(32), d_in[6]=res_r(8) — compile-time constants here
  const float* W1   = (const float*)d_in[7];
  const float* b1   = (const float*)d_in[8];
  const float* W2   = (const float*)d_in[9];
  const float* b2   = (const float*)d_in[10];
  const float* Wg   = (const float*)d_in[11];
  const float* Wc31 = (const float*)d_in[12];
  const float* bc31 = (const float*)d_in[13];
  const float* Wc32 = (const float*)d_in[14];
  const float* bc32 = (const float*)d_in[15];

  float* ws    = (float*)d_ws;
  float* ft    = ws;                            // 65536 floats
  _Float16* h2H = (_Float16*)(ws + 65536);      // 524288 halfs (262144 floats)
  _Float16* h2L = (_Float16*)(ws + 327680);     // 524288 halfs
  float* WS    = ws + 589824;                   // 512
  unsigned* uftg = (unsigned*)(ws + 590336);    // 256 uints (encoded max)
  unsigned* cnt  = (unsigned*)(ws + 590592);    // 1 uint
  float* wq    = ws + 606720;                   // 32
  float* sgs   = ws + 606752;                   // 64
  _Float16* VswH  = (_Float16*)(ws + 606816);   // 131072 f16
  _Float16* VswL  = (_Float16*)(ws + 672352);   // 131072 f16
  _Float16* W2swH = (_Float16*)(ws + 737888);   // 2048 f16
  _Float16* W2swL = (_Float16*)(ws + 738912);   // 2048 f16
  float* out   = (float*)d_out;                 // 8388608
  float* ftg   = out + 8388608;                 // 256

  hipMemsetAsync(ft, 0, 65536*sizeof(float), stream);
  k_scatter<<<1024, 256, 0, stream>>>(inputs, scale, sigma, A, icmp, Wg,
                                      ft, wq, sgs, WS, uftg, cnt);
  k_conv12<<<256, 512, 0, stream>>>(ft, W1, b1, W2, b2, wq, Wg, Wc31, Wc32,
                                    VswH, VswL, W2swH, W2swL, h2H, h2L, WS);
  k_head<<<512, 512, 0, stream>>>(h2H, h2L, WS, sgs, Wc31, bc31, bc32,
                                  (const half8*)VswH, (const half8*)VswL,
                                  (const half8*)W2swH, (const half8*)W2swL,
                                  out, uftg, cnt, ftg);
}

// Round 3
// 153.663 us; speedup vs baseline: 1.6193x; 1.6193x over previous
//
#include <hip/hip_runtime.h>
#include <math.h>

#define PI_D 3.14159265358979323846
#define PI_F 3.14159265358979323846f

typedef _Float16 half8 __attribute__((ext_vector_type(8)));
typedef _Float16 half4v __attribute__((ext_vector_type(4)));
typedef float floatx4 __attribute__((ext_vector_type(4)));
#define MFMA16(a,b,c) __builtin_amdgcn_mfma_f32_16x16x32_f16(a,b,c,0,0,0)

// order-preserving float<->uint encoding for atomicMax on floats
__device__ __forceinline__ unsigned fenc(float f) {
  unsigned u = __float_as_uint(f);
  return (u & 0x80000000u) ? ~u : (u | 0x80000000u);
}
__device__ __forceinline__ float fdec(unsigned e) {
  return (e & 0x80000000u) ? __uint_as_float(e & 0x7FFFFFFFu)
                           : __uint_as_float(~e);
}

// ---------------- scatter + small prep (wq block0; sgs/WS/uftg zero block1) ----------------
__global__ void k_scatter(const float* __restrict__ inp,
                          const float* __restrict__ p_scale,
                          const float* __restrict__ p_sigma,
                          const float* __restrict__ p_A,
                          const float* __restrict__ p_ic,
                          const float* __restrict__ Wg,
                          float* __restrict__ ft, float* __restrict__ wq,
                          float* __restrict__ sgs, float* __restrict__ WS,
                          unsigned* __restrict__ uftg) {
  int blk = blockIdx.x, t = threadIdx.x;
  if (blk == 0) {
    // quadrature weights, fp64 kept for bit-identical wq, k-sum spread
    // over 8 lanes per j (2 serial sins/lane instead of 17).
    double jj = 2.0*(double)(t >> 3) + 1.0;
    int kk = t & 7;
    double s = 0.0;
#pragma unroll
    for (int u = 0; u < 2; ++u) {
      double k2 = (double)(2*(kk + 8*u) + 1);
      s += sin(jj * k2 * (PI_D/64.0)) / k2;
    }
    s += __shfl_xor(s, 1, 64);
    s += __shfl_xor(s, 2, 64);
    s += __shfl_xor(s, 4, 64);
    if (kk == 0) wq[t >> 3] = (float)((2.0/16.0) * sin(PI_D * jj / 64.0) * s);
  } else if (blk == 1) {
    if (t < 64) {                                  // sgs[c] = sum_g Wg[c,g]
      float s = 0.f;
      for (int g = 0; g < 32; ++g) s += Wg[t*32 + g];
      sgs[t] = s;
    } else if (t < 192) {                          // zero WS (512 floats, float4)
      ((float4*)WS)[t - 64] = make_float4(0.f, 0.f, 0.f, 0.f);
    } else {                                       // zero uftg (256 uints; enc identity)
      uint4 z; z.x = z.y = z.z = z.w = 0u;
      ((uint4*)uftg)[t - 192] = z;
    }
  }
  int i = blk * 256 + t;                           // 0 .. 262143
  float scale = p_scale[0];
  float sigma = p_sigma[0];
  float A     = p_A[0];
  float icomp = p_ic[0];
  int b = i >> 15;
  float x = inp[i*3+0];
  float y = inp[i*3+1];
  float z = inp[i*3+2];
  float r = sqrtf(x*x + y*y + z*z);
  r = fmaxf(r, 0.1f);
  float ctv = fminf(fmaxf(z / r, -1.0f), 1.0f);
  float theta = acosf(ctv);
  float phi = atan2f(y, x) + PI_F;
  float ct = theta * (32.0f / PI_F);
  float cp = phi * (32.0f / (2.0f * PI_F));
  float cr = r / scale * 8.0f;
  int it = (int)floorf(ct); it = min(max(it, 0), 31);
  int ip = (int)floorf(cp); ip = min(max(ip, 0), 31);
  int ir = (int)floorf(cr); ir = min(max(ir, 0), 7);
  float dt = ct - ((float)it + icomp);
  float dp = cp - ((float)ip + icomp);
  float dr = cr - ((float)ir + icomp);
  float d2 = dt*dt + dp*dp + dr*dr;
  float w = A * expf(-d2 / (2.0f * sigma * sigma));
  atomicAdd(&ft[((b*8 + ir)*32 + it)*32 + ip], w);
}

// ---------------- fused conv1+conv2+reduce + V/W2 fragment prep ----------------
__global__ __launch_bounds__(512) void k_conv12(
    const float* __restrict__ ft, const float* __restrict__ W1,
    const float* __restrict__ b1, const float* __restrict__ W2,
    const float* __restrict__ b2, const float* __restrict__ wq,
    const float* __restrict__ Wg, const float* __restrict__ Wc31,
    const float* __restrict__ Wc32,
    _Float16* __restrict__ VswH, _Float16* __restrict__ VswL,
    _Float16* __restrict__ W2swH, _Float16* __restrict__ W2swL,
    _Float16* __restrict__ h2H, _Float16* __restrict__ h2L,
    float* __restrict__ WS) {
  __shared__ __align__(16) float ftt[8][5][32];    // [ic][xx][y]
  __shared__ __align__(16) float h1t[32][3][32];   // [ic2][xr][y]
  __shared__ __align__(16) float W1s[72*34];       // [rest][oc2], pad 34 (b64 reads)
  __shared__ __align__(16) float W2s[288*68];      // [rest][oc], pad 68 (b128 reads)
  int blk = blockIdx.x;
  int b = blk >> 5, xt = blk & 31;
  int t = threadIdx.x;                             // 512

  // ---- fragment prep (for k_head), disjoint chunks ----
  {
    int flat = blk * 512 + t;                      // 0 .. 131071
    int jj = flat & 7;
    int l  = (flat >> 3) & 63;
    int rest = flat >> 9;                          // mt*2 + ks
    int ks = rest & 1, mt = rest >> 1;
    int c = ks*32 + (l >> 4)*8 + jj;
    int m = mt*16 + (l & 15);                      // m = g*64 + d
    int g = m >> 6, d = m & 63;
    float val = Wg[c*32 + g] * Wc31[d*128 + c];
    _Float16 hi = (_Float16)val;
    VswH[flat] = hi;
    VswL[flat] = (_Float16)(val - (float)hi);
    if (flat < 2048) {                             // W2 A-frags (M-side = e)
      int ks2 = rest & 1, mt2 = rest >> 1;
      int e = mt2*16 + (l & 15);
      int dd = ks2*32 + (l >> 4)*8 + jj;
      float v2 = Wc32[e*64 + dd];
      _Float16 h2i = (_Float16)v2;
      W2swH[flat] = h2i;
      W2swL[flat] = (_Float16)(v2 - (float)h2i);
    }
  }

  // ---- coalesced weight staging w/ padded transpose ----
  for (int idx = t; idx < 2304; idx += 512) {      // W1: read flat (coalesced)
    int oc2 = idx / 72, rest = idx % 72;
    W1s[rest*34 + oc2] = W1[idx];
  }
  for (int idx = t; idx < 4608; idx += 512) {      // W2: float4 coalesced
    float4 v4 = ((const float4*)W2)[idx];
    int base = idx * 4;
    int oc = base / 288, r0 = base % 288;
    W2s[(r0+0)*68 + oc] = v4.x;
    W2s[(r0+1)*68 + oc] = v4.y;
    W2s[(r0+2)*68 + oc] = v4.z;
    W2s[(r0+3)*68 + oc] = v4.w;
  }
  for (int idx = t; idx < 1280; idx += 512) {
    int y = idx & 31, xx = (idx >> 5) % 5, ic = idx / 160;
    int xg = xt + xx - 2;
    ftt[ic][xx][y] = ((unsigned)xg < 32u) ? ft[b*8192 + ic*1024 + xg*32 + y] : 0.f;
  }
  __syncthreads();

  // ---- conv1: thread owns oc2 = grp*2+{0,1}, xr = 0..2, one y ----
  {
    int y = t & 31, grp = t >> 5;
    float acc[2][3];
    float bb0 = b1[grp*2+0], bb1 = b1[grp*2+1];
#pragma unroll
    for (int xr = 0; xr < 3; ++xr) { acc[0][xr] = bb0; acc[1][xr] = bb1; }
    for (int ic = 0; ic < 8; ++ic) {
      float v[5][3];
#pragma unroll
      for (int dyi = 0; dyi < 3; ++dyi) {
        int yy = y + dyi - 1;
        bool ok = ((unsigned)yy < 32u);
        int yc = min(max(yy, 0), 31);
#pragma unroll
        for (int xx = 0; xx < 5; ++xx) {
          float tv = ftt[ic][xx][yc];
          v[xx][dyi] = ok ? tv : 0.f;
        }
      }
#pragma unroll
      for (int k = 0; k < 9; ++k) {
        float2 w01 = *(const float2*)&W1s[(ic*9 + k)*34 + grp*2];
        int dx = k / 3, dy = k % 3;
#pragma unroll
        for (int xr = 0; xr < 3; ++xr) {
          float vv = v[xr + dx][dy];
          acc[0][xr] = fmaf(vv, w01.x, acc[0][xr]);
          acc[1][xr] = fmaf(vv, w01.y, acc[1][xr]);
        }
      }
    }
#pragma unroll
    for (int xr = 0; xr < 3; ++xr) {
      int xg = xt + xr - 1;
      bool ok = ((unsigned)xg < 32u);
      h1t[grp*2+0][xr][y] = ok ? fmaxf(acc[0][xr], 0.f) : 0.f;
      h1t[grp*2+1][xr][y] = ok ? fmaxf(acc[1][xr], 0.f) : 0.f;
    }
  }
  __syncthreads();

  // ---- conv2 + f16-split store + reduce: thread owns oc = og*4..+3, one y ----
  {
    int y = t & 31, og = t >> 5, oc0 = og*4;
    float a0 = b2[oc0+0], a1 = b2[oc0+1], a2 = b2[oc0+2], a3 = b2[oc0+3];
    for (int ic2 = 0; ic2 < 32; ++ic2) {
      float v[3][3];
#pragma unroll
      for (int dyi = 0; dyi < 3; ++dyi) {
        int yy = y + dyi - 1;
        bool ok = ((unsigned)yy < 32u);
        int yc = min(max(yy, 0), 31);
#pragma unroll
        for (int xxi = 0; xxi < 3; ++xxi) {
          float tv = h1t[ic2][xxi][yc];
          v[xxi][dyi] = ok ? tv : 0.f;
        }
      }
#pragma unroll
      for (int k = 0; k < 9; ++k) {
        float4 wv = *(const float4*)&W2s[(ic2*9 + k)*68 + oc0];
        float vv = v[k/3][k%3];
        a0 = fmaf(vv, wv.x, a0);
        a1 = fmaf(vv, wv.y, a1);
        a2 = fmaf(vv, wv.z, a2);
        a3 = fmaf(vv, wv.w, a3);
      }
    }
    float r0 = fmaxf(a0, 0.f), r1 = fmaxf(a1, 0.f);
    float r2 = fmaxf(a2, 0.f), r3 = fmaxf(a3, 0.f);
    // store h2 pre-split to f16 hi/lo in k_head B-fragment layout:
    // frag idx = (((b*32+x)*2 + ks)*4 + quad)*32 + col, elem j; c = ks*32+quad*8+j
    int ks = og >> 3, quad = (og >> 1) & 3, jb = (og & 1) * 4;
    int fidx = (((b*32 + xt)*2 + ks)*4 + quad)*32 + y;
    half4v hv, lv;
    hv[0] = (_Float16)r0; lv[0] = (_Float16)(r0 - (float)hv[0]);
    hv[1] = (_Float16)r1; lv[1] = (_Float16)(r1 - (float)hv[1]);
    hv[2] = (_Float16)r2; lv[2] = (_Float16)(r2 - (float)hv[2]);
    hv[3] = (_Float16)r3; lv[3] = (_Float16)(r3 - (float)hv[3]);
    *(half4v*)&h2H[(size_t)fidx*8 + jb] = hv;
    *(half4v*)&h2L[(size_t)fidx*8 + jb] = lv;
    float wqv = wq[y];
    float s0 = r0*wqv, s1 = r1*wqv, s2 = r2*wqv, s3 = r3*wqv;
#pragma unroll
    for (int m = 1; m < 32; m <<= 1) {
      s0 += __shfl_xor(s0, m, 64);
      s1 += __shfl_xor(s1, m, 64);
      s2 += __shfl_xor(s2, m, 64);
      s3 += __shfl_xor(s3, m, 64);
    }
    if ((t & 31) == 0) {
      atomicAdd(&WS[b*64 + oc0+0], s0);
      atomicAdd(&WS[b*64 + oc0+1], s1);
      atomicAdd(&WS[b*64 + oc0+2], s2);
      atomicAdd(&WS[b*64 + oc0+3], s3);
    }
  }
}

// ---------------- head (MFMA): grid 512 = b(8)*x(32)*h(2), h = g-half ----
// tail: 32 lanes/block do flip-encoded atomicMax into uftg (no fence!)
__global__ __launch_bounds__(512, 4) void k_head(
    const _Float16* __restrict__ h2H, const _Float16* __restrict__ h2L,
    const float* __restrict__ WS, const float* __restrict__ sgs,
    const float* __restrict__ Wc31, const float* __restrict__ bc31,
    const float* __restrict__ bc32,
    const half8* __restrict__ VswH, const half8* __restrict__ VswL,
    const half8* __restrict__ W2swH, const half8* __restrict__ W2swL,
    float* __restrict__ out, unsigned* __restrict__ uftg) {
  __shared__ __align__(16) _Float16 h3H[512*72];   // [rowc=y*16+gl][d sw], 72 KiB
  __shared__ float Ks[64];
  __shared__ float vbuf2[128];
  int blk = blockIdx.x;            // 512
  int b = blk >> 6, x = (blk >> 1) & 31, h = blk & 1;
  int t = threadIdx.x;             // 512 = 8 waves
  int lane = t & 63, w = t >> 6;
  int n16 = lane & 15, quad = lane >> 4;

  // Ks[d] = bc31[d] + sum_c Wc31[d,64+c]*sgs[c]*WS[b,c], 4 lanes per d
  if (t < 256) {
    int d = t >> 2, q = t & 3;
    const float* wr  = Wc31 + d*128 + 64 + q*16;
    const float* sg  = sgs + q*16;
    const float* wsb = WS + b*64 + q*16;
    float acc = 0.f;
#pragma unroll
    for (int c = 0; c < 16; ++c)
      acc = fmaf(wr[c], sg[c]*wsb[c], acc);
    acc += __shfl_xor(acc, 1, 64);
    acc += __shfl_xor(acc, 2, 64);
    if (q == 0) Ks[d] = acc + bc31[d];
  }

  // GEMM1 B-frags: direct coalesced half8 loads (pre-split by k_conv12)
  half8 bh00, bh01, bh10, bh11, bl00, bl01, bl10, bl11;
  {
    const half8* H8 = (const half8*)h2H;
    const half8* L8 = (const half8*)h2L;
    int fo = ((b*32 + x)*8 + quad)*32;       // ks=0 base; ks=1 at +128
    bh00 = H8[fo + n16];        bh10 = H8[fo + 16 + n16];
    bl00 = L8[fo + n16];        bl10 = L8[fo + 16 + n16];
    bh01 = H8[fo + 128 + n16];  bh11 = H8[fo + 128 + 16 + n16];
    bl01 = L8[fo + 128 + n16];  bl11 = L8[fo + 128 + 16 + n16];
  }
  int mt2 = w & 1;
  half8 a2h0 = W2swH[(mt2*2 + 0)*64 + lane];
  half8 a2h1 = W2swH[(mt2*2 + 1)*64 + lane];
  half8 a2l0 = W2swL[(mt2*2 + 0)*64 + lane];
  half8 a2l1 = W2swL[(mt2*2 + 1)*64 + lane];
  float bias_e[4];
#pragma unroll
  for (int r = 0; r < 4; ++r) bias_e[r] = bc32[mt2*16 + quad*4 + r];
  __syncthreads();                 // Ks ready

  // ---- phase A: GEMM1, wave owns mt = h*64 + w*8 + i ----
  for (int i = 0; i < 8; ++i) {
    int mt = h*64 + w*8 + i;
    half8 ah0 = VswH[(mt*2 + 0)*64 + lane];
    half8 ah1 = VswH[(mt*2 + 1)*64 + lane];
    half8 al0 = VswL[(mt*2 + 0)*64 + lane];
    half8 al1 = VswL[(mt*2 + 1)*64 + lane];
    floatx4 acc0 = {0.f, 0.f, 0.f, 0.f};
    floatx4 acc1 = {0.f, 0.f, 0.f, 0.f};
    acc0 = MFMA16(ah0, bh00, acc0);  acc1 = MFMA16(ah0, bh10, acc1);
    acc0 = MFMA16(ah0, bl00, acc0);  acc1 = MFMA16(ah0, bl10, acc1);
    acc0 = MFMA16(al0, bh00, acc0);  acc1 = MFMA16(al0, bh10, acc1);
    acc0 = MFMA16(ah1, bh01, acc0);  acc1 = MFMA16(ah1, bh11, acc1);
    acc0 = MFMA16(ah1, bl01, acc0);  acc1 = MFMA16(ah1, bl11, acc1);
    acc0 = MFMA16(al1, bh01, acc0);  acc1 = MFMA16(al1, bh11, acc1);
    int g = mt >> 2, gl = g & 15;
    int dbase = (mt & 3)*16 + quad*4;
    float4 kv = *(const float4*)&Ks[dbase];
#pragma unroll
    for (int nt = 0; nt < 2; ++nt) {
      floatx4 a = nt ? acc1 : acc0;
      int y = nt*16 + n16;
      int rowc = y*16 + gl;
      int dsw = (dbase + y*8) & 63;
      half4v hv;
      hv[0] = (_Float16)fmaxf(a[0] + kv.x, 0.f);
      hv[1] = (_Float16)fmaxf(a[1] + kv.y, 0.f);
      hv[2] = (_Float16)fmaxf(a[2] + kv.z, 0.f);
      hv[3] = (_Float16)fmaxf(a[3] + kv.w, 0.f);
      *(half4v*)&h3H[rowc*72 + dsw] = hv;
    }
  }
  __syncthreads();
  // ---- phase B: GEMM2, wave owns nt2 = (w>>1)*8 + i (= y), e-tile mt2 ----
  float vmax[4] = {-3.4e38f, -3.4e38f, -3.4e38f, -3.4e38f};
  for (int i = 0; i < 8; ++i) {
    int nt2 = (w >> 1)*8 + i;
    int rowc = nt2*16 + n16;       // gl = n16
    int dsw0 = (quad*8 + nt2*8) & 63;
    int dsw1 = (32 + quad*8 + nt2*8) & 63;
    half8 b2h0 = *(const half8*)&h3H[rowc*72 + dsw0];
    half8 b2h1 = *(const half8*)&h3H[rowc*72 + dsw1];
    floatx4 acc = {0.f, 0.f, 0.f, 0.f};
    acc = MFMA16(a2h0, b2h0, acc);
    acc = MFMA16(a2l0, b2h0, acc);
    acc = MFMA16(a2h1, b2h1, acc);
    acc = MFMA16(a2l1, b2h1, acc);
    int y = nt2, g = h*16 + n16;
    size_t base = (((size_t)(b*32 + mt2*16 + quad*4))*1024 + (size_t)(x*32 + y))*32 + g;
#pragma unroll
    for (int r = 0; r < 4; ++r) {
      float v = acc[r] + bias_e[r];
      out[base + (size_t)r*32768] = v;
      vmax[r] = fmaxf(vmax[r], v);
    }
  }
  // block max over e
#pragma unroll
  for (int m = 1; m < 16; m <<= 1) {
#pragma unroll
    for (int r = 0; r < 4; ++r)
      vmax[r] = fmaxf(vmax[r], __shfl_xor(vmax[r], m, 64));
  }
  if (n16 == 0) {
#pragma unroll
    for (int r = 0; r < 4; ++r) vbuf2[w*16 + quad*4 + r] = vmax[r];
  }
  __syncthreads();
  if (t < 32) {
    int e = t, m2 = e >> 4, el = e & 15;
    float mm = fmaxf(fmaxf(vbuf2[(m2+0)*16 + el], vbuf2[(m2+2)*16 + el]),
                     fmaxf(vbuf2[(m2+4)*16 + el], vbuf2[(m2+6)*16 + el]));
    atomicMax(&uftg[b*32 + e], fenc(mm));
  }
}

// ---------------- finalize: decode 256 encoded maxima ----------------
__global__ void k_final(const unsigned* __restrict__ uftg, float* __restrict__ ftg) {
  int t = threadIdx.x;             // 256
  ftg[t] = fdec(uftg[t]);
}

extern "C" void kernel_launch(void* const* d_in, const int* in_sizes, int n_in,
                              void* d_out, int out_size, void* d_ws, size_t ws_size,
                              hipStream_t stream) {
  const float* inputs = (const float*)d_in[0];
  const float* scale  = (const float*)d_in[1];
  const float* sigma  = (const float*)d_in[2];
  const float* A      = (const float*)d_in[3];
  const float* icmp   = (const float*)d_in[4];
  // d_in[5]=res_pt(32), d_in[6]=res_r(8) — compile-time constants here
  const float* W1   = (const float*)d_in[7];
  const float* b1   = (const float*)d_in[8];
  const float* W2   = (const float*)d_in[9];
  const float* b2   = (const float*)d_in[10];
  const float* Wg   = (const float*)d_in[11];
  const float* Wc31 = (const float*)d_in[12];
  const float* bc31 = (const float*)d_in[13];
  const float* Wc32 = (const float*)d_in[14];
  const float* bc32 = (const float*)d_in[15];

  float* ws    = (float*)d_ws;
  float* ft    = ws;                            // 65536 floats
  _Float16* h2H = (_Float16*)(ws + 65536);      // 524288 halfs (262144 floats)
  _Float16* h2L = (_Float16*)(ws + 327680);     // 524288 halfs
  float* WS    = ws + 589824;                   // 512
  unsigned* uftg = (unsigned*)(ws + 590336);    // 256 uints (encoded max)
  float* wq    = ws + 606720;                   // 32
  float* sgs   = ws + 606752;                   // 64
  _Float16* VswH  = (_Float16*)(ws + 606816);   // 131072 f16
  _Float16* VswL  = (_Float16*)(ws + 672352);   // 131072 f16
  _Float16* W2swH = (_Float16*)(ws + 737888);   // 2048 f16
  _Float16* W2swL = (_Float16*)(ws + 738912);   // 2048 f16
  float* out   = (float*)d_out;                 // 8388608
  float* ftg   = out + 8388608;                 // 256

  hipMemsetAsync(ft, 0, 65536*sizeof(float), stream);
  k_scatter<<<1024, 256, 0, stream>>>(inputs, scale, sigma, A, icmp, Wg,
                                      ft, wq, sgs, WS, uftg);
  k_conv12<<<256, 512, 0, stream>>>(ft, W1, b1, W2, b2, wq, Wg, Wc31, Wc32,
                                    VswH, VswL, W2swH, W2swL, h2H, h2L, WS);
  k_head<<<512, 512, 0, stream>>>(h2H, h2L, WS, sgs, Wc31, bc31, bc32,
                                  (const half8*)VswH, (const half8*)VswL,
                                  (const half8*)W2swH, (const half8*)W2swL,
                                  out, uftg);
  k_final<<<1, 256, 0, stream>>>(uftg, ftg);
}